// Round 1
// baseline (82.564 us; speedup 1.0000x reference)
//
#include <hip/hip_runtime.h>
#include <math.h>

#define BS 8
#define NF 32
#define MAXC 4
#define NLOC 65536
#define DELTA_VAR 0.5f
#define DELTA_DIST 1.5f
#define GAMMA 1e-4f

// workspace layout (float offsets)
#define WS_SUMS   0      // [BS][NF][MAXC] = 1024
#define WS_COUNTS 1024   // [BS][MAXC]     = 32
#define WS_MEANS  1056   // [BS][NF][MAXC] = 1024
#define WS_M2     2080   // [BS][MAXC]     = 32
#define WS_VARSUM 2112   // [BS][MAXC]     = 32
#define WS_TOTAL  2144

#define GRIDX 64   // blocks per batch; chunk = NLOC/GRIDX = 1024

// Pass 1: sums[b][f][c] = sum_n input[b,f,n]*target[b,c,n]; counts[b][c].
// Block: 256 threads = 4 waves; wave w owns f in [w*8, w*8+8); 64 lanes own
// float4-vectorized n. All loads 16B/lane coalesced.
__global__ __launch_bounds__(256) void k_sums(const float* __restrict__ inp,
                                              const float* __restrict__ tgt,
                                              float* __restrict__ ws) {
  float* sums = ws + WS_SUMS;
  float* counts = ws + WS_COUNTS;
  const int b = blockIdx.y;
  const int lane = threadIdx.x & 63;
  const int fg = threadIdx.x >> 6;  // 0..3
  const int chunk = NLOC / GRIDX;
  const int n0 = blockIdx.x * chunk;
  const float* inp_b = inp + (size_t)b * NF * NLOC;
  const float* tgt_b = tgt + (size_t)b * MAXC * NLOC;

  float acc[8][4];
#pragma unroll
  for (int i = 0; i < 8; ++i) {
#pragma unroll
    for (int c = 0; c < 4; ++c) acc[i][c] = 0.f;
  }
  float cnt[4] = {0.f, 0.f, 0.f, 0.f};

  for (int nb = n0; nb < n0 + chunk; nb += 256) {
    const int n = nb + lane * 4;
    float4 t[4];
#pragma unroll
    for (int c = 0; c < 4; ++c)
      t[c] = *reinterpret_cast<const float4*>(tgt_b + c * NLOC + n);
    if (fg == 0) {
#pragma unroll
      for (int c = 0; c < 4; ++c) cnt[c] += t[c].x + t[c].y + t[c].z + t[c].w;
    }
#pragma unroll
    for (int i = 0; i < 8; ++i) {
      const int f = fg * 8 + i;
      float4 x = *reinterpret_cast<const float4*>(inp_b + f * NLOC + n);
#pragma unroll
      for (int c = 0; c < 4; ++c)
        acc[i][c] += x.x * t[c].x + x.y * t[c].y + x.z * t[c].z + x.w * t[c].w;
    }
  }
#pragma unroll
  for (int i = 0; i < 8; ++i) {
#pragma unroll
    for (int c = 0; c < 4; ++c) {
      float v = acc[i][c];
#pragma unroll
      for (int m = 1; m < 64; m <<= 1) v += __shfl_xor(v, m, 64);
      if (lane == 0) atomicAdd(&sums[(b * NF + fg * 8 + i) * MAXC + c], v);
    }
  }
  if (fg == 0) {
#pragma unroll
    for (int c = 0; c < 4; ++c) {
      float v = cnt[c];
#pragma unroll
      for (int m = 1; m < 64; m <<= 1) v += __shfl_xor(v, m, 64);
      if (lane == 0) atomicAdd(&counts[b * MAXC + c], v);
    }
  }
}

// means[b][f][c] = active ? sums/counts : 0 ; M2[b][c] = sum_f mean^2
__global__ void k_means(float* __restrict__ ws) {
  const float* sums = ws + WS_SUMS;
  const float* counts = ws + WS_COUNTS;
  float* means = ws + WS_MEANS;
  float* M2 = ws + WS_M2;
  const int i = blockIdx.x * 256 + threadIdx.x;  // 0..1023 = ((b*NF+f)*4+c)
  const int c = i & 3;
  const int b = i >> 7;
  const float cnt = counts[b * 4 + c];
  const float m = cnt > 0.f ? sums[i] / cnt : 0.f;
  means[i] = m;
  atomicAdd(&M2[b * 4 + c], m * m);
}

// Pass 2: varsum[b][c] = sum_n max(||x_n - m_c|| - dv, 0)^2 * t[c,n]
// using ||x-m||^2 = ||x||^2 - 2 x.m + ||m||^2 (means staged in LDS).
__global__ __launch_bounds__(256) void k_var(const float* __restrict__ inp,
                                             const float* __restrict__ tgt,
                                             float* __restrict__ ws) {
  const float* means = ws + WS_MEANS;
  const float* M2 = ws + WS_M2;
  float* varsum = ws + WS_VARSUM;
  const int b = blockIdx.y;

  __shared__ float4 m_lds[NF];
  __shared__ float m2_lds[4];
  __shared__ float vred[4][4];
  if (threadIdx.x < NF)
    m_lds[threadIdx.x] =
        reinterpret_cast<const float4*>(means + (size_t)b * NF * 4)[threadIdx.x];
  if (threadIdx.x < 4) m2_lds[threadIdx.x] = M2[b * 4 + threadIdx.x];
  __syncthreads();

  const int chunk = NLOC / GRIDX;  // 1024
  const int n0 = blockIdx.x * chunk;
  const float* inp_b = inp + (size_t)b * NF * NLOC;
  const float* tgt_b = tgt + (size_t)b * MAXC * NLOC;

  const float m2c0 = m2_lds[0], m2c1 = m2_lds[1], m2c2 = m2_lds[2], m2c3 = m2_lds[3];
  float vacc[4] = {0.f, 0.f, 0.f, 0.f};

  for (int n = n0 + threadIdx.x * 4; n < n0 + chunk; n += 1024) {
    float4 s2 = {0.f, 0.f, 0.f, 0.f};
    float4 d0 = {0.f, 0.f, 0.f, 0.f}, d1 = d0, d2 = d0, d3 = d0;
#pragma unroll
    for (int f = 0; f < NF; ++f) {
      float4 x = *reinterpret_cast<const float4*>(inp_b + f * NLOC + n);
      float4 m4 = m_lds[f];
      s2.x += x.x * x.x; s2.y += x.y * x.y; s2.z += x.z * x.z; s2.w += x.w * x.w;
      d0.x += x.x * m4.x; d0.y += x.y * m4.x; d0.z += x.z * m4.x; d0.w += x.w * m4.x;
      d1.x += x.x * m4.y; d1.y += x.y * m4.y; d1.z += x.z * m4.y; d1.w += x.w * m4.y;
      d2.x += x.x * m4.z; d2.y += x.y * m4.z; d2.z += x.z * m4.z; d2.w += x.w * m4.z;
      d3.x += x.x * m4.w; d3.y += x.y * m4.w; d3.z += x.z * m4.w; d3.w += x.w * m4.w;
    }
    const float4* dptr[4] = {&d0, &d1, &d2, &d3};
    const float m2arr[4] = {m2c0, m2c1, m2c2, m2c3};
#pragma unroll
    for (int c = 0; c < 4; ++c) {
      float4 t = *reinterpret_cast<const float4*>(tgt_b + c * NLOC + n);
      float4 dd = *dptr[c];
      float sqx = s2.x - 2.f * dd.x + m2arr[c];
      float sqy = s2.y - 2.f * dd.y + m2arr[c];
      float sqz = s2.z - 2.f * dd.z + m2arr[c];
      float sqw = s2.w - 2.f * dd.w + m2arr[c];
      float dx = sqx > 0.f ? sqrtf(sqx) : 0.f;
      float dy = sqy > 0.f ? sqrtf(sqy) : 0.f;
      float dz = sqz > 0.f ? sqrtf(sqz) : 0.f;
      float dw = sqw > 0.f ? sqrtf(sqw) : 0.f;
      float vx = fmaxf(dx - DELTA_VAR, 0.f);
      float vy = fmaxf(dy - DELTA_VAR, 0.f);
      float vz = fmaxf(dz - DELTA_VAR, 0.f);
      float vw = fmaxf(dw - DELTA_VAR, 0.f);
      vacc[c] += vx * vx * t.x + vy * vy * t.y + vz * vz * t.z + vw * vw * t.w;
    }
  }

  const int lane = threadIdx.x & 63;
  const int wave = threadIdx.x >> 6;
  float vr[4];
#pragma unroll
  for (int c = 0; c < 4; ++c) {
    float v = vacc[c];
#pragma unroll
    for (int m = 1; m < 64; m <<= 1) v += __shfl_xor(v, m, 64);
    vr[c] = v;
  }
  if (lane == 0) {
#pragma unroll
    for (int c = 0; c < 4; ++c) vred[wave][c] = vr[c];
  }
  __syncthreads();
  if (threadIdx.x < 4) {
    const int c = threadIdx.x;
    float s = vred[0][c] + vred[1][c] + vred[2][c] + vred[3][c];
    atomicAdd(&varsum[b * 4 + c], s);
  }
}

// Epilogue: l_var + l_dist + GAMMA*l_reg -> out[0]
__global__ void k_final(const float* __restrict__ ws,
                        const int* __restrict__ n_clusters,
                        float* __restrict__ out) {
  const float* counts = ws + WS_COUNTS;
  const float* means = ws + WS_MEANS;
  const float* varsum = ws + WS_VARSUM;
  const int lane = threadIdx.x;
  float total = 0.f;
  if (lane < BS) {
    const int b = lane;
    const float nc = (float)n_clusters[b];
    // l_var component
    float sv = 0.f;
    for (int c = 0; c < MAXC; ++c) {
      float cntc = counts[b * 4 + c];
      if (cntc > 0.f) sv += varsum[b * 4 + c] / cntc;
    }
    float l_var = sv / nc;
    // l_dist + l_reg over K_ACTIVE=2 clusters (per reference slicing)
    float d2 = 0.f, n0s = 0.f, n1s = 0.f;
    for (int f = 0; f < NF; ++f) {
      float m0 = means[(b * NF + f) * 4 + 0];
      float m1 = means[(b * NF + f) * 4 + 1];
      float df = m0 - m1;
      d2 += df * df;
      n0s += m0 * m0;
      n1s += m1 * m1;
    }
    float dn = d2 > 0.f ? sqrtf(d2) : 0.f;
    float h = fmaxf(2.f * DELTA_DIST - dn, 0.f);
    float c_dist = 2.f * h * h;  // pairs (0,1) and (1,0); diagonal is 0
    float l_dist = c_dist / (2.f * nc * (nc - 1.f));
    float r0 = n0s > 0.f ? sqrtf(n0s) : 0.f;
    float r1 = n1s > 0.f ? sqrtf(n1s) : 0.f;
    float l_reg = 0.5f * (r0 + r1);
    total = l_var + l_dist + GAMMA * l_reg;
  }
#pragma unroll
  for (int m = 1; m < 8; m <<= 1) total += __shfl_xor(total, m, 64);
  if (lane == 0) out[0] = total / (float)BS;
}

extern "C" void kernel_launch(void* const* d_in, const int* in_sizes, int n_in,
                              void* d_out, int out_size, void* d_ws, size_t ws_size,
                              hipStream_t stream) {
  const float* inp = (const float*)d_in[0];
  const float* tgt = (const float*)d_in[1];
  const int* ncl = (const int*)d_in[2];
  float* out = (float*)d_out;
  float* ws = (float*)d_ws;

  hipMemsetAsync(d_ws, 0, WS_TOTAL * sizeof(float), stream);
  dim3 grid(GRIDX, BS);
  k_sums<<<grid, 256, 0, stream>>>(inp, tgt, ws);
  k_means<<<4, 256, 0, stream>>>(ws);
  k_var<<<grid, 256, 0, stream>>>(inp, tgt, ws);
  k_final<<<1, 64, 0, stream>>>(ws, ncl, out);
}

// Round 2
// 39.945 us; speedup vs baseline: 2.0669x; 2.0669x over previous
//
#include <hip/hip_runtime.h>
#include <math.h>

#define BS 8
#define NF 32
#define MAXC 4
#define NLOC 65536
#define DELTA_VAR 0.5f
#define DELTA_DIST 1.5f
#define GAMMA 1e-4f

// workspace layout (float offsets)
#define WS_COUNTS 0      // [BS][MAXC] = 32
#define WS_MEANS  32     // [BS][NF][MAXC] = 1024
#define WS_M2     1056   // [BS][MAXC] = 32
#define WS_VARSUM 1088   // [BS][MAXC] padded x32 floats (one line each) = 1024
#define WS_PART   2112   // [BS][G][132] partials (128 sums + 4 counts)

// -------- Pass 1: per-block partial sums (no atomics) --------------------
// grid (G, BS), block 256 = 4 waves; wave fg owns features fg*8..fg*8+7.
// Tail: transposed butterfly leaves out[k] (k=(lane>>1)&31) in each lane,
// LDS-combine across waves, one coalesced 132-float store per block.
template <int G>
__global__ __launch_bounds__(256, 4) void k_sums(const float* __restrict__ inp,
                                                 const float* __restrict__ tgt,
                                                 float* __restrict__ ws) {
  constexpr int CHUNK = NLOC / G;
  float* part = ws + WS_PART;
  const int b = blockIdx.y;
  const int gx = blockIdx.x;
  const int lane = threadIdx.x & 63;
  const int fg = threadIdx.x >> 6;
  const int n0 = gx * CHUNK;
  const float* inp_b = inp + (size_t)b * NF * NLOC + (size_t)fg * 8 * NLOC;
  const float* tgt_b = tgt + (size_t)b * MAXC * NLOC;

  float r[32];
#pragma unroll
  for (int k = 0; k < 32; ++k) r[k] = 0.f;
  float cnt0 = 0.f, cnt1 = 0.f, cnt2 = 0.f, cnt3 = 0.f;

#pragma unroll
  for (int it = 0; it < CHUNK / 256; ++it) {
    const int n = n0 + it * 256 + lane * 4;
    float4 t0 = *reinterpret_cast<const float4*>(tgt_b + 0 * NLOC + n);
    float4 t1 = *reinterpret_cast<const float4*>(tgt_b + 1 * NLOC + n);
    float4 t2 = *reinterpret_cast<const float4*>(tgt_b + 2 * NLOC + n);
    float4 t3 = *reinterpret_cast<const float4*>(tgt_b + 3 * NLOC + n);
    float4 x[8];
#pragma unroll
    for (int i = 0; i < 8; ++i)
      x[i] = *reinterpret_cast<const float4*>(inp_b + i * NLOC + n);
    if (fg == 0) {
      cnt0 += t0.x + t0.y + t0.z + t0.w;
      cnt1 += t1.x + t1.y + t1.z + t1.w;
      cnt2 += t2.x + t2.y + t2.z + t2.w;
      cnt3 += t3.x + t3.y + t3.z + t3.w;
    }
#pragma unroll
    for (int i = 0; i < 8; ++i) {
      r[i * 4 + 0] += x[i].x * t0.x + x[i].y * t0.y + x[i].z * t0.z + x[i].w * t0.w;
      r[i * 4 + 1] += x[i].x * t1.x + x[i].y * t1.y + x[i].z * t1.z + x[i].w * t1.w;
      r[i * 4 + 2] += x[i].x * t2.x + x[i].y * t2.y + x[i].z * t2.z + x[i].w * t2.w;
      r[i * 4 + 3] += x[i].x * t3.x + x[i].y * t3.y + x[i].z * t3.z + x[i].w * t3.w;
    }
  }

  // transposed butterfly: 32 values over 64 lanes -> lane l holds out[(l>>1)&31]
#define BSTEP(m, half)                                   \
  {                                                      \
    _Pragma("unroll") for (int j = 0; j < half; ++j) {   \
      float aa = __shfl_xor(r[j], m, 64);                \
      float bb = __shfl_xor(r[j + half], m, 64);         \
      r[j] = (lane & m) ? (r[j + half] + bb) : (r[j] + aa); \
    }                                                    \
  }
  BSTEP(32, 16)
  BSTEP(16, 8)
  BSTEP(8, 4)
  BSTEP(4, 2)
  BSTEP(2, 1)
#undef BSTEP
  r[0] += __shfl_xor(r[0], 1, 64);

  __shared__ float pp[132];
  if (!(lane & 1)) pp[fg * 32 + (lane >> 1)] = r[0];

  if (fg == 0) {
    // 4 counts over 64 lanes: lane bits {5,4} select, then full reduce bits 3..0
    float aa = __shfl_xor(cnt0, 32, 64), bb = __shfl_xor(cnt2, 32, 64);
    float u0 = (lane & 32) ? (cnt2 + bb) : (cnt0 + aa);
    aa = __shfl_xor(cnt1, 32, 64); bb = __shfl_xor(cnt3, 32, 64);
    float u1 = (lane & 32) ? (cnt3 + bb) : (cnt1 + aa);
    aa = __shfl_xor(u0, 16, 64); bb = __shfl_xor(u1, 16, 64);
    float u = (lane & 16) ? (u1 + bb) : (u0 + aa);
    u += __shfl_xor(u, 8, 64);
    u += __shfl_xor(u, 4, 64);
    u += __shfl_xor(u, 2, 64);
    u += __shfl_xor(u, 1, 64);
    if ((lane & 15) == 0) pp[128 + (lane >> 4)] = u;
  }
  __syncthreads();
  if (threadIdx.x < 132)
    part[((size_t)(b * G + gx)) * 132 + threadIdx.x] = pp[threadIdx.x];
}

// -------- Reduce partials -> counts, means, M2; zero varsum ---------------
// grid BS, block 512.
template <int G>
__global__ __launch_bounds__(512) void k_reduce(float* __restrict__ ws) {
  const float* part = ws + WS_PART;
  const int b = blockIdx.x;
  const int t = threadIdx.x;
  __shared__ float cbuf[G][4];
  __shared__ float sbuf[4][128];
  __shared__ float cnts[4];
  __shared__ float m2buf[128];
  const float* pb = part + (size_t)b * G * 132;

  if (t < G) {
    float4 c4 = *reinterpret_cast<const float4*>(pb + (size_t)t * 132 + 128);
    cbuf[t][0] = c4.x; cbuf[t][1] = c4.y; cbuf[t][2] = c4.z; cbuf[t][3] = c4.w;
  }
  __syncthreads();
  if (t < 4) {
    float s = 0.f;
#pragma unroll 8
    for (int g = 0; g < G; ++g) s += cbuf[g][t];
    cnts[t] = s;
    ws[WS_COUNTS + b * 4 + t] = s;
    ws[WS_VARSUM + (b * 4 + t) * 32] = 0.f;
  }
  // partial sums of the 128 (f,c) outputs, 4 g-slices in parallel
  const int rem = t & 127, q = t >> 7;
  float s = 0.f;
  for (int g = q * (G / 4); g < (q + 1) * (G / 4); ++g)
    s += pb[(size_t)g * 132 + rem];
  sbuf[q][rem] = s;
  __syncthreads();
  if (t < 128) {
    float tot = sbuf[0][t] + sbuf[1][t] + sbuf[2][t] + sbuf[3][t];
    float cnt = cnts[t & 3];
    float mean = cnt > 0.f ? tot / cnt : 0.f;
    ws[WS_MEANS + b * 128 + t] = mean;
    m2buf[t] = mean * mean;
  }
  __syncthreads();
  if (t < 4) {
    float s2 = 0.f;
#pragma unroll
    for (int f = 0; f < 32; ++f) s2 += m2buf[f * 4 + t];
    ws[WS_M2 + b * 4 + t] = s2;
  }
}

// -------- Pass 2: varsum via ||x-m||^2 = ||x||^2 - 2 x.m + ||m||^2 -------
// grid (128, BS), block 256; each thread owns 2 locations (float2 loads).
__global__ __launch_bounds__(256, 4) void k_var(const float* __restrict__ inp,
                                                const float* __restrict__ tgt,
                                                float* __restrict__ ws) {
  const int b = blockIdx.y;
  __shared__ float4 m_lds[NF];
  __shared__ float m2_lds[4];
  __shared__ float vred[4][4];
  if (threadIdx.x < NF)
    m_lds[threadIdx.x] =
        reinterpret_cast<const float4*>(ws + WS_MEANS + b * 128)[threadIdx.x];
  if (threadIdx.x < 4) m2_lds[threadIdx.x] = ws[WS_M2 + b * 4 + threadIdx.x];
  __syncthreads();

  const int n = blockIdx.x * 512 + threadIdx.x * 2;
  const float* inp_b = inp + (size_t)b * NF * NLOC;
  const float* tgt_b = tgt + (size_t)b * MAXC * NLOC;

  float s2x = 0.f, s2y = 0.f;
  float d0x = 0.f, d0y = 0.f, d1x = 0.f, d1y = 0.f;
  float d2x = 0.f, d2y = 0.f, d3x = 0.f, d3y = 0.f;
#pragma unroll
  for (int f = 0; f < NF; ++f) {
    float2 x = *reinterpret_cast<const float2*>(inp_b + f * NLOC + n);
    float4 m4 = m_lds[f];
    s2x += x.x * x.x; s2y += x.y * x.y;
    d0x += x.x * m4.x; d0y += x.y * m4.x;
    d1x += x.x * m4.y; d1y += x.y * m4.y;
    d2x += x.x * m4.z; d2y += x.y * m4.z;
    d3x += x.x * m4.w; d3y += x.y * m4.w;
  }

  float vacc0, vacc1, vacc2, vacc3;
#define VARC(c, dx_, dy_, dst)                                        \
  {                                                                   \
    float2 tt = *reinterpret_cast<const float2*>(tgt_b + c * NLOC + n); \
    float m2c = m2_lds[c];                                            \
    float sqx = s2x - 2.f * dx_ + m2c;                                \
    float sqy = s2y - 2.f * dy_ + m2c;                                \
    float ddx = sqx > 0.f ? sqrtf(sqx) : 0.f;                         \
    float ddy = sqy > 0.f ? sqrtf(sqy) : 0.f;                         \
    float vx = fmaxf(ddx - DELTA_VAR, 0.f);                           \
    float vy = fmaxf(ddy - DELTA_VAR, 0.f);                           \
    dst = vx * vx * tt.x + vy * vy * tt.y;                            \
  }
  VARC(0, d0x, d0y, vacc0)
  VARC(1, d1x, d1y, vacc1)
  VARC(2, d2x, d2y, vacc2)
  VARC(3, d3x, d3y, vacc3)
#undef VARC

  const int lane = threadIdx.x & 63;
  const int wave = threadIdx.x >> 6;
  float aa = __shfl_xor(vacc0, 32, 64), bb = __shfl_xor(vacc2, 32, 64);
  float u0 = (lane & 32) ? (vacc2 + bb) : (vacc0 + aa);
  aa = __shfl_xor(vacc1, 32, 64); bb = __shfl_xor(vacc3, 32, 64);
  float u1 = (lane & 32) ? (vacc3 + bb) : (vacc1 + aa);
  aa = __shfl_xor(u0, 16, 64); bb = __shfl_xor(u1, 16, 64);
  float u = (lane & 16) ? (u1 + bb) : (u0 + aa);
  u += __shfl_xor(u, 8, 64);
  u += __shfl_xor(u, 4, 64);
  u += __shfl_xor(u, 2, 64);
  u += __shfl_xor(u, 1, 64);
  if ((lane & 15) == 0) vred[wave][lane >> 4] = u;
  __syncthreads();
  if (threadIdx.x < 4) {
    const int c = threadIdx.x;
    float s = vred[0][c] + vred[1][c] + vred[2][c] + vred[3][c];
    atomicAdd(&ws[WS_VARSUM + (b * 4 + c) * 32], s);
  }
}

// -------- Epilogue --------------------------------------------------------
__global__ void k_final(const float* __restrict__ ws,
                        const int* __restrict__ n_clusters,
                        float* __restrict__ out) {
  const int lane = threadIdx.x;
  float total = 0.f;
  if (lane < BS) {
    const int b = lane;
    const float nc = (float)n_clusters[b];
    float sv = 0.f;
    for (int c = 0; c < MAXC; ++c) {
      float cntc = ws[WS_COUNTS + b * 4 + c];
      if (cntc > 0.f) sv += ws[WS_VARSUM + (b * 4 + c) * 32] / cntc;
    }
    float l_var = sv / nc;
    float d2 = 0.f, n0s = 0.f, n1s = 0.f;
    for (int f = 0; f < NF; ++f) {
      float m0 = ws[WS_MEANS + (b * NF + f) * 4 + 0];
      float m1 = ws[WS_MEANS + (b * NF + f) * 4 + 1];
      float df = m0 - m1;
      d2 += df * df;
      n0s += m0 * m0;
      n1s += m1 * m1;
    }
    float dn = d2 > 0.f ? sqrtf(d2) : 0.f;
    float h = fmaxf(2.f * DELTA_DIST - dn, 0.f);
    float c_dist = 2.f * h * h;
    float l_dist = c_dist / (2.f * nc * (nc - 1.f));
    float r0 = n0s > 0.f ? sqrtf(n0s) : 0.f;
    float r1 = n1s > 0.f ? sqrtf(n1s) : 0.f;
    float l_reg = 0.5f * (r0 + r1);
    total = l_var + l_dist + GAMMA * l_reg;
  }
#pragma unroll
  for (int m = 1; m < 8; m <<= 1) total += __shfl_xor(total, m, 64);
  if (lane == 0) out[0] = total / (float)BS;
}

extern "C" void kernel_launch(void* const* d_in, const int* in_sizes, int n_in,
                              void* d_out, int out_size, void* d_ws, size_t ws_size,
                              hipStream_t stream) {
  const float* inp = (const float*)d_in[0];
  const float* tgt = (const float*)d_in[1];
  const int* ncl = (const int*)d_in[2];
  float* out = (float*)d_out;
  float* ws = (float*)d_ws;

  const size_t need128 = (size_t)(2112 + 8 * 128 * 132) * 4;
  if (ws_size >= need128) {
    k_sums<128><<<dim3(128, BS), 256, 0, stream>>>(inp, tgt, ws);
    k_reduce<128><<<BS, 512, 0, stream>>>(ws);
  } else {
    k_sums<32><<<dim3(32, BS), 256, 0, stream>>>(inp, tgt, ws);
    k_reduce<32><<<BS, 512, 0, stream>>>(ws);
  }
  k_var<<<dim3(128, BS), 256, 0, stream>>>(inp, tgt, ws);
  k_final<<<1, 64, 0, stream>>>(ws, ncl, out);
}

// Round 3
// 35.869 us; speedup vs baseline: 2.3018x; 1.1136x over previous
//
#include <hip/hip_runtime.h>
#include <math.h>

#define BS 8
#define NF 32
#define MAXC 4
#define NLOC 65536
#define DELTA_VAR 0.5f
#define DELTA_DIST 1.5f
#define GAMMA 1e-4f

// workspace layout (float offsets)
#define WS_COUNTS 0      // [BS][MAXC] = 32
#define WS_MEANS  32     // [BS][NF][MAXC] = 1024
#define WS_M2     1056   // [BS][MAXC] = 32
#define WS_VARSUM 1088   // [BS][MAXC] padded x32 floats (one line each) = 1024
#define WS_PART   2112   // [BS][G][68] partials: 64 (f x {sx,s0}) + cnt0
#define GG 128
#define PART_SZ (BS * GG * 68)
// labels (uint8 [BS][NLOC]) live right after partials

// -------- Pass 1: read input + target row 0 only ------------------------
// Exploits one-hot target with labels in {0,1}: t1 = 1 - t0, t2 = t3 = 0.
// Per feature accumulate sx = sum(x), s0 = sum(x*t0). Emits labels (u8).
// grid (GG, BS), block 256 = 4 waves; wave fg owns features fg*8..fg*8+7.
__global__ __launch_bounds__(256, 4) void k_sums(const float* __restrict__ inp,
                                                 const float* __restrict__ tgt,
                                                 float* __restrict__ ws,
                                                 unsigned char* __restrict__ labels) {
  constexpr int CHUNK = NLOC / GG;  // 512
  float* part = ws + WS_PART;
  const int b = blockIdx.y;
  const int gx = blockIdx.x;
  const int lane = threadIdx.x & 63;
  const int fg = threadIdx.x >> 6;
  const int n0 = gx * CHUNK;
  const float* inp_b = inp + (size_t)b * NF * NLOC + (size_t)fg * 8 * NLOC;
  const float* tgt_b = tgt + (size_t)b * MAXC * NLOC;  // row 0

  float r[16];  // r[i*2+0]=sx_i, r[i*2+1]=s0_i
#pragma unroll
  for (int k = 0; k < 16; ++k) r[k] = 0.f;
  float cnt0 = 0.f;

#pragma unroll
  for (int it = 0; it < CHUNK / 256; ++it) {
    const int n = n0 + it * 256 + lane * 4;
    float4 t0 = *reinterpret_cast<const float4*>(tgt_b + n);
    float4 x[8];
#pragma unroll
    for (int i = 0; i < 8; ++i)
      x[i] = *reinterpret_cast<const float4*>(inp_b + i * NLOC + n);
    if (fg == 0) {
      cnt0 += t0.x + t0.y + t0.z + t0.w;
      uchar4 l4;
      l4.x = t0.x > 0.5f ? 0 : 1;
      l4.y = t0.y > 0.5f ? 0 : 1;
      l4.z = t0.z > 0.5f ? 0 : 1;
      l4.w = t0.w > 0.5f ? 0 : 1;
      *reinterpret_cast<uchar4*>(labels + (size_t)b * NLOC + n) = l4;
    }
#pragma unroll
    for (int i = 0; i < 8; ++i) {
      r[i * 2 + 0] += x[i].x + x[i].y + x[i].z + x[i].w;
      r[i * 2 + 1] += x[i].x * t0.x + x[i].y * t0.y + x[i].z * t0.z + x[i].w * t0.w;
    }
  }

  // transposed butterfly: 16 values over 64 lanes -> lane l holds out[(l>>2)&15]
#define BSTEP(m, half)                                      \
  {                                                         \
    _Pragma("unroll") for (int j = 0; j < half; ++j) {      \
      float aa = __shfl_xor(r[j], m, 64);                   \
      float bb = __shfl_xor(r[j + half], m, 64);            \
      r[j] = (lane & m) ? (r[j + half] + bb) : (r[j] + aa); \
    }                                                       \
  }
  BSTEP(32, 8)
  BSTEP(16, 4)
  BSTEP(8, 2)
  BSTEP(4, 1)
#undef BSTEP
  r[0] += __shfl_xor(r[0], 2, 64);
  r[0] += __shfl_xor(r[0], 1, 64);

  __shared__ float pp[68];
  if ((lane & 3) == 0) pp[fg * 16 + (lane >> 2)] = r[0];

  if (fg == 0) {
    cnt0 += __shfl_xor(cnt0, 32, 64);
    cnt0 += __shfl_xor(cnt0, 16, 64);
    cnt0 += __shfl_xor(cnt0, 8, 64);
    cnt0 += __shfl_xor(cnt0, 4, 64);
    cnt0 += __shfl_xor(cnt0, 2, 64);
    cnt0 += __shfl_xor(cnt0, 1, 64);
    if (lane == 0) pp[64] = cnt0;
  }
  __syncthreads();
  if (threadIdx.x < 65)
    part[((size_t)(b * GG + gx)) * 68 + threadIdx.x] = pp[threadIdx.x];
}

// -------- Reduce partials -> counts, means, M2; zero varsum ---------------
__global__ __launch_bounds__(512) void k_reduce(float* __restrict__ ws) {
  const float* part = ws + WS_PART;
  const int b = blockIdx.x;
  const int t = threadIdx.x;
  __shared__ float sbuf[8][64];
  __shared__ float cbuf[GG];
  __shared__ float tbuf[64];
  __shared__ float cnt_s[2];
  __shared__ float m2buf[2][32];
  const float* pb = part + (size_t)b * GG * 68;

  {
    const int rem = t & 63, q = t >> 6;
    float s = 0.f;
    for (int g = q * (GG / 8); g < (q + 1) * (GG / 8); ++g)
      s += pb[(size_t)g * 68 + rem];
    sbuf[q][rem] = s;
  }
  if (t < GG) cbuf[t] = pb[(size_t)t * 68 + 64];
  __syncthreads();
  if (t < 64) {
    float s = 0.f;
#pragma unroll
    for (int q = 0; q < 8; ++q) s += sbuf[q][t];
    tbuf[t] = s;
  }
  if (t == 64) {
    float c = 0.f;
    for (int g = 0; g < GG; ++g) c += cbuf[g];
    cnt_s[0] = c;
    cnt_s[1] = (float)NLOC - c;
  }
  __syncthreads();
  if (t < 32) {
    float sx = tbuf[t * 2], s0 = tbuf[t * 2 + 1];
    float c0 = cnt_s[0], c1 = cnt_s[1];
    float mean0 = c0 > 0.f ? s0 / c0 : 0.f;
    float mean1 = c1 > 0.f ? (sx - s0) / c1 : 0.f;
    ws[WS_MEANS + b * 128 + t * 4 + 0] = mean0;
    ws[WS_MEANS + b * 128 + t * 4 + 1] = mean1;
    ws[WS_MEANS + b * 128 + t * 4 + 2] = 0.f;
    ws[WS_MEANS + b * 128 + t * 4 + 3] = 0.f;
    m2buf[0][t] = mean0 * mean0;
    m2buf[1][t] = mean1 * mean1;
  }
  __syncthreads();
  if (t < 2) {
    float m2 = 0.f;
#pragma unroll
    for (int f = 0; f < 32; ++f) m2 += m2buf[t][f];
    ws[WS_M2 + b * 4 + t] = m2;
  } else if (t < 4) {
    ws[WS_M2 + b * 4 + t] = 0.f;
  } else if (t < 8) {
    const int c = t - 4;
    ws[WS_COUNTS + b * 4 + c] = c < 2 ? cnt_s[c] : 0.f;
  } else if (t < 12) {
    ws[WS_VARSUM + (b * 4 + (t - 8)) * 32] = 0.f;
  }
}

// -------- Pass 2: input + labels only ------------------------------------
// ||x-m||^2 = ||x||^2 - 2 x.m + ||m||^2; only the labeled cluster counts.
__global__ __launch_bounds__(256, 4) void k_var(const float* __restrict__ inp,
                                                const unsigned char* __restrict__ labels,
                                                float* __restrict__ ws) {
  const int b = blockIdx.y;
  __shared__ float2 m_lds[NF];  // (mean0, mean1) per feature
  __shared__ float m2_s[2];
  __shared__ float vred[4][2];
  if (threadIdx.x < NF) {
    const float* mb = ws + WS_MEANS + b * 128 + threadIdx.x * 4;
    m_lds[threadIdx.x] = make_float2(mb[0], mb[1]);
  }
  if (threadIdx.x < 2) m2_s[threadIdx.x] = ws[WS_M2 + b * 4 + threadIdx.x];
  __syncthreads();

  const int n = blockIdx.x * 512 + threadIdx.x * 2;
  const float* inp_b = inp + (size_t)b * NF * NLOC;
  const uchar2 lab = *reinterpret_cast<const uchar2*>(labels + (size_t)b * NLOC + n);

  float s2x = 0.f, s2y = 0.f;
  float d0x = 0.f, d0y = 0.f, d1x = 0.f, d1y = 0.f;
#pragma unroll
  for (int f = 0; f < NF; ++f) {
    float2 x = *reinterpret_cast<const float2*>(inp_b + f * NLOC + n);
    float2 m = m_lds[f];
    s2x += x.x * x.x; s2y += x.y * x.y;
    d0x += x.x * m.x; d0y += x.y * m.x;
    d1x += x.x * m.y; d1y += x.y * m.y;
  }

  float vacc0 = 0.f, vacc1 = 0.f;
  {
    const float d = lab.x ? d1x : d0x;
    const float m2 = lab.x ? m2_s[1] : m2_s[0];
    float sq = s2x - 2.f * d + m2;
    float dist = sq > 0.f ? sqrtf(sq) : 0.f;
    float v = fmaxf(dist - DELTA_VAR, 0.f);
    float vv = v * v;
    vacc0 += lab.x ? 0.f : vv;
    vacc1 += lab.x ? vv : 0.f;
  }
  {
    const float d = lab.y ? d1y : d0y;
    const float m2 = lab.y ? m2_s[1] : m2_s[0];
    float sq = s2y - 2.f * d + m2;
    float dist = sq > 0.f ? sqrtf(sq) : 0.f;
    float v = fmaxf(dist - DELTA_VAR, 0.f);
    float vv = v * v;
    vacc0 += lab.y ? 0.f : vv;
    vacc1 += lab.y ? vv : 0.f;
  }

  const int lane = threadIdx.x & 63;
  const int wave = threadIdx.x >> 6;
  float aa = __shfl_xor(vacc0, 32, 64);
  float bb = __shfl_xor(vacc1, 32, 64);
  float u = (lane & 32) ? (vacc1 + bb) : (vacc0 + aa);
  u += __shfl_xor(u, 16, 64);
  u += __shfl_xor(u, 8, 64);
  u += __shfl_xor(u, 4, 64);
  u += __shfl_xor(u, 2, 64);
  u += __shfl_xor(u, 1, 64);
  if ((lane & 31) == 0) vred[wave][lane >> 5] = u;
  __syncthreads();
  if (threadIdx.x < 2) {
    const int c = threadIdx.x;
    float s = vred[0][c] + vred[1][c] + vred[2][c] + vred[3][c];
    atomicAdd(&ws[WS_VARSUM + (b * 4 + c) * 32], s);
  }
}

// -------- Epilogue --------------------------------------------------------
__global__ void k_final(const float* __restrict__ ws,
                        const int* __restrict__ n_clusters,
                        float* __restrict__ out) {
  const int lane = threadIdx.x;
  float total = 0.f;
  if (lane < BS) {
    const int b = lane;
    const float nc = (float)n_clusters[b];
    float sv = 0.f;
    for (int c = 0; c < MAXC; ++c) {
      float cntc = ws[WS_COUNTS + b * 4 + c];
      if (cntc > 0.f) sv += ws[WS_VARSUM + (b * 4 + c) * 32] / cntc;
    }
    float l_var = sv / nc;
    float d2 = 0.f, n0s = 0.f, n1s = 0.f;
    for (int f = 0; f < NF; ++f) {
      float m0 = ws[WS_MEANS + (b * NF + f) * 4 + 0];
      float m1 = ws[WS_MEANS + (b * NF + f) * 4 + 1];
      float df = m0 - m1;
      d2 += df * df;
      n0s += m0 * m0;
      n1s += m1 * m1;
    }
    float dn = d2 > 0.f ? sqrtf(d2) : 0.f;
    float h = fmaxf(2.f * DELTA_DIST - dn, 0.f);
    float c_dist = 2.f * h * h;
    float l_dist = c_dist / (2.f * nc * (nc - 1.f));
    float r0 = n0s > 0.f ? sqrtf(n0s) : 0.f;
    float r1 = n1s > 0.f ? sqrtf(n1s) : 0.f;
    float l_reg = 0.5f * (r0 + r1);
    total = l_var + l_dist + GAMMA * l_reg;
  }
#pragma unroll
  for (int m = 1; m < 8; m <<= 1) total += __shfl_xor(total, m, 64);
  if (lane == 0) out[0] = total / (float)BS;
}

extern "C" void kernel_launch(void* const* d_in, const int* in_sizes, int n_in,
                              void* d_out, int out_size, void* d_ws, size_t ws_size,
                              hipStream_t stream) {
  const float* inp = (const float*)d_in[0];
  const float* tgt = (const float*)d_in[1];
  const int* ncl = (const int*)d_in[2];
  float* out = (float*)d_out;
  float* ws = (float*)d_ws;
  unsigned char* labels = (unsigned char*)(ws + WS_PART + PART_SZ);

  k_sums<<<dim3(GG, BS), 256, 0, stream>>>(inp, tgt, ws, labels);
  k_reduce<<<BS, 512, 0, stream>>>(ws);
  k_var<<<dim3(128, BS), 256, 0, stream>>>(inp, labels, ws);
  k_final<<<1, 64, 0, stream>>>(ws, ncl, out);
}